// Round 1
// baseline (938.689 us; speedup 1.0000x reference)
//
#include <hip/hip_runtime.h>
#include <hip/hip_bf16.h>
#include <stdint.h>

#define CLASSES 100000
#define CHANNEL 128
#define BATCH   4096
#define NPAD    100032   // 1563 * 64 (N padded to tile multiple)

typedef __bf16 bf16x8 __attribute__((ext_vector_type(8)));
typedef float  f32x4  __attribute__((ext_vector_type(4)));
typedef unsigned short u16x8 __attribute__((ext_vector_type(8)));

__device__ __forceinline__ unsigned short f32_to_bf16_rne(float f) {
    union { float f; uint32_t u; } v; v.f = f;
    uint32_t u = v.u;
    return (unsigned short)((u + 0x7fffu + ((u >> 16) & 1u)) >> 16);
}

// One wave per row: normalize x rows, write bf16.
__global__ void xnorm_kernel(const float* __restrict__ x, unsigned short* __restrict__ xn) {
    const int row  = blockIdx.x;
    const int lane = threadIdx.x;            // 0..63
    const float2 v = *reinterpret_cast<const float2*>(&x[(size_t)row * CHANNEL + lane * 2]);
    float s = v.x * v.x + v.y * v.y;
    #pragma unroll
    for (int off = 32; off >= 1; off >>= 1) s += __shfl_xor(s, off);
    const float inv = rsqrtf(fmaxf(s, 1e-12f));
    ushort2 o;
    o.x = f32_to_bf16_rne(v.x * inv);
    o.y = f32_to_bf16_rne(v.y * inv);
    *reinterpret_cast<ushort2*>(&xn[(size_t)row * CHANNEL + lane * 2]) = o;
}

// One thread per class-column: L2-normalize w column k, write transposed
// bf16 row wnt[k][0..127]. Two-pass read of w (second pass is L2/LLC-hot).
__global__ void wnorm_kernel(const float* __restrict__ w, unsigned short* __restrict__ wnt) {
    const int k = blockIdx.x * 256 + threadIdx.x;
    if (k >= NPAD) return;
    if (k >= CLASSES) {
        // zero-fill pad rows so MFMA on pad columns is harmless
        u16x8 z;
        #pragma unroll
        for (int i = 0; i < 8; ++i) z[i] = 0;
        #pragma unroll
        for (int c = 0; c < CHANNEL; c += 8)
            *reinterpret_cast<u16x8*>(&wnt[(size_t)k * CHANNEL + c]) = z;
        return;
    }
    float s = 0.f;
    #pragma unroll 8
    for (int c = 0; c < CHANNEL; ++c) {
        const float v = w[(size_t)c * CLASSES + k];
        s += v * v;
    }
    const float inv = rsqrtf(fmaxf(s, 1e-12f));
    #pragma unroll
    for (int c0 = 0; c0 < CHANNEL; c0 += 8) {
        u16x8 o;
        #pragma unroll
        for (int i = 0; i < 8; ++i) {
            const float v = w[(size_t)(c0 + i) * CLASSES + k];
            o[i] = f32_to_bf16_rne(v * inv);
        }
        *reinterpret_cast<u16x8*>(&wnt[(size_t)k * CHANNEL + c0]) = o;
    }
}

// 64x64 output tile per block, 4 waves stacked along M (16 rows x 64 cols each).
// K = 128 = 4 MFMA steps of 32. A and B fragments loaded directly from
// global (A tile 1 MB total; per-block B tile 16 KB -> L1/L2 resident).
__global__ __launch_bounds__(256) void cos_gemm_kernel(const unsigned short* __restrict__ xn,
                                                       const unsigned short* __restrict__ wnt,
                                                       float* __restrict__ out) {
    const int bm   = blockIdx.x;     // 0..63   (M tiles; fastest -> consecutive blocks share B tile)
    const int bn   = blockIdx.y;     // 0..1562 (N tiles)
    const int tid  = threadIdx.x;
    const int wid  = tid >> 6;       // 0..3
    const int lane = tid & 63;
    const int l15  = lane & 15;
    const int lg   = lane >> 4;      // 0..3

    const int arow  = bm * 64 + wid * 16 + l15;
    const int ncol0 = bn * 64;
    const unsigned short* ap = &xn[(size_t)arow * CHANNEL + lg * 8];

    f32x4 acc[4] = {};
    #pragma unroll
    for (int ks = 0; ks < 4; ++ks) {
        const bf16x8 a = *reinterpret_cast<const bf16x8*>(ap + ks * 32);
        #pragma unroll
        for (int nf = 0; nf < 4; ++nf) {
            const unsigned short* bp =
                &wnt[(size_t)(ncol0 + nf * 16 + l15) * CHANNEL + ks * 32 + lg * 8];
            const bf16x8 b = *reinterpret_cast<const bf16x8*>(bp);
            acc[nf] = __builtin_amdgcn_mfma_f32_16x16x32_bf16(a, b, acc[nf], 0, 0, 0);
        }
    }

    // C/D layout: col = lane&15, row = (lane>>4)*4 + reg  [HW-verified]
    const int orow0 = bm * 64 + wid * 16 + lg * 4;
    #pragma unroll
    for (int nf = 0; nf < 4; ++nf) {
        const int col = ncol0 + nf * 16 + l15;
        if (col < CLASSES) {
            #pragma unroll
            for (int j = 0; j < 4; ++j) {
                __builtin_nontemporal_store(acc[nf][j], &out[(size_t)(orow0 + j) * CLASSES + col]);
            }
        }
    }
}

extern "C" void kernel_launch(void* const* d_in, const int* in_sizes, int n_in,
                              void* d_out, int out_size, void* d_ws, size_t ws_size,
                              hipStream_t stream) {
    const float* x = (const float*)d_in[0];   // (4096, 128)
    const float* w = (const float*)d_in[1];   // (128, 100000)
    float* out = (float*)d_out;               // (4096, 100000)

    unsigned short* xn  = (unsigned short*)d_ws;                       // 4096*128 bf16 = 1 MiB
    unsigned short* wnt = xn + (size_t)BATCH * CHANNEL;                // 100032*128 bf16 = 25.6 MB
    const size_t need = ((size_t)BATCH * CHANNEL + (size_t)NPAD * CHANNEL) * sizeof(unsigned short);
    if (ws_size < need) return;  // insufficient scratch -> fail visibly rather than corrupt

    xnorm_kernel<<<dim3(BATCH), dim3(64), 0, stream>>>(x, xn);
    wnorm_kernel<<<dim3((NPAD + 255) / 256), dim3(256), 0, stream>>>(w, wnt);
    cos_gemm_kernel<<<dim3(64, 1563), dim3(256), 0, stream>>>(xn, wnt, out);
}